// Round 8
// baseline (210.943 us; speedup 1.0000x reference)
//
#include <hip/hip_runtime.h>
#include <stdint.h>

#define L_SEQ 2048
#define DIM 1536
#define NH 24
#define HD 64
#define NQKV 4608
#define KVSPLIT 2
#define KVHALF (L_SEQ / KVSPLIT)

typedef unsigned short u16;
typedef __attribute__((ext_vector_type(4))) float f32x4;
typedef __attribute__((ext_vector_type(8))) short bf16x8;
typedef __attribute__((ext_vector_type(4))) u16 u16x4;
typedef __attribute__((ext_vector_type(8))) u16 u16x8;

__device__ __forceinline__ u16 f2bf(float f) {
  unsigned u = __builtin_bit_cast(unsigned, f);
  u += 0x7fffu + ((u >> 16) & 1u);
  return (u16)(u >> 16);
}
__device__ __forceinline__ float b2f(u16 u) {
  return __builtin_bit_cast(float, (unsigned)u << 16);
}

__device__ __forceinline__ void gload_lds16(const void* g, void* lds) {
  __builtin_amdgcn_global_load_lds(
      (const __attribute__((address_space(1))) unsigned int*)g,
      (__attribute__((address_space(3))) unsigned int*)lds, 16, 0, 0);
}

// ---------------- cast f32 -> bf16 ----------------
__global__ __launch_bounds__(256) void cast_kernel(const float* __restrict__ in,
                                                   u16* __restrict__ out, int n4) {
  int i = blockIdx.x * 256 + threadIdx.x;
  if (i >= n4) return;
  f32x4 v = ((const f32x4*)in)[i];
  u16x4 o;
  o.x = f2bf(v.x);
  o.y = f2bf(v.y);
  o.z = f2bf(v.z);
  o.w = f2bf(v.w);
  ((u16x4*)out)[i] = o;
}

// ---------------- GEMM: C[M][N] = A[M][K] * B[N][K]^T + bias ----------------
// m97-style: 128x128 tile, BK=32, 4 waves (2x2), 16x16x32 MFMA, global_load_lds.
template <int WRITE_BF16>
__global__ __launch_bounds__(256) void gemm_bt(const u16* __restrict__ A,
                                               const u16* __restrict__ B,
                                               const float* __restrict__ bias,
                                               void* __restrict__ Cout,
                                               int M, int N, int K) {
  __shared__ u16 As[128 * 32];
  __shared__ u16 Bs[128 * 32];
  const int nb = N >> 7;
  const int bx = (int)blockIdx.x % nb;
  const int by = (int)blockIdx.x / nb;
  const int tid = threadIdx.x;
  const int lane = tid & 63;
  const int wv = tid >> 6;
  const int wr = wv >> 1, wc = wv & 1;

  f32x4 acc[4][4];
#pragma unroll
  for (int i = 0; i < 4; i++)
#pragma unroll
    for (int j = 0; j < 4; j++) acc[i][j] = (f32x4)(0.0f);

  const int e0 = tid * 8;
  const int r0 = e0 >> 5, c0 = e0 & 31;
  const u16* Ag0 = A + (size_t)(by * 128 + r0) * K + c0;
  const u16* Ag1 = A + (size_t)(by * 128 + r0 + 64) * K + c0;
  const u16* Bg0 = B + (size_t)(bx * 128 + r0) * K + c0;
  const u16* Bg1 = B + (size_t)(bx * 128 + r0 + 64) * K + c0;
  char* AsB = (char*)As + wv * 1024;  // wave-uniform LDS base (+ lane*16 by HW)
  char* BsB = (char*)Bs + wv * 1024;
  const int kc = (lane >> 4) * 8;

  for (int k0 = 0; k0 < K; k0 += 32) {
    __syncthreads();
    gload_lds16(Ag0 + k0, AsB);
    gload_lds16(Ag1 + k0, AsB + 4096);
    gload_lds16(Bg0 + k0, BsB);
    gload_lds16(Bg1 + k0, BsB + 4096);
    __syncthreads();

    bf16x8 af[4], bfr[4];
#pragma unroll
    for (int mt = 0; mt < 4; mt++)
      af[mt] = *(const bf16x8*)&As[(wr * 64 + mt * 16 + (lane & 15)) * 32 + kc];
#pragma unroll
    for (int nt = 0; nt < 4; nt++)
      bfr[nt] = *(const bf16x8*)&Bs[(wc * 64 + nt * 16 + (lane & 15)) * 32 + kc];
#pragma unroll
    for (int mt = 0; mt < 4; mt++)
#pragma unroll
      for (int nt = 0; nt < 4; nt++)
        acc[mt][nt] = __builtin_amdgcn_mfma_f32_16x16x32_bf16(af[mt], bfr[nt],
                                                              acc[mt][nt], 0, 0, 0);
  }

  // C/D layout: col = lane&15, row = (lane>>4)*4 + reg
  const int colb = bx * 128 + wc * 64 + (lane & 15);
  const int rowb = by * 128 + wr * 64 + ((lane >> 4) << 2);
#pragma unroll
  for (int nt = 0; nt < 4; nt++) {
    const int col = colb + nt * 16;
    const float bv = bias[col];
#pragma unroll
    for (int mt = 0; mt < 4; mt++) {
#pragma unroll
      for (int r = 0; r < 4; r++) {
        const int row = rowb + mt * 16 + r;
        float v = acc[mt][nt][r] + bv;
        if (WRITE_BF16)
          ((u16*)Cout)[(size_t)row * N + col] = f2bf(v);
        else
          ((float*)Cout)[(size_t)row * N + col] = v;
      }
    }
  }
}

// ---------------- QK-RMSNorm + layout rearrange (bf16 qkv input) ------------
// Q additionally scaled by log2(e)/8 so attention scores are in log2 domain.
__global__ __launch_bounds__(256) void qkvnorm_kernel(const u16* __restrict__ qkv,
                                                      const float* __restrict__ gq,
                                                      const float* __restrict__ gk,
                                                      u16* __restrict__ Qh,
                                                      u16* __restrict__ Kh,
                                                      u16* __restrict__ Vt) {
  const int h = blockIdx.y;
  const int lblk = blockIdx.x * 64;
  const int tid = threadIdx.x;
  const int lane = tid & 63, wv = tid >> 6;
  __shared__ u16 vt[64][64];
  const float gqv = gq[lane] * 0.125f * 1.44269504088896f;  // 1/sqrt(HD) * log2(e)
  const float gkv = gk[lane];
#pragma unroll 1
  for (int i = 0; i < 16; i++) {
    const int l = lblk + wv * 16 + i;
    const size_t base = (size_t)l * NQKV + h * HD + lane;
    const float q = b2f(qkv[base]);
    const float k = b2f(qkv[base + DIM]);
    float sq = q * q, sk = k * k;
#pragma unroll
    for (int m = 32; m; m >>= 1) {
      sq += __shfl_xor(sq, m);
      sk += __shfl_xor(sk, m);
    }
    const float rq = rsqrtf(sq * (1.0f / 64.0f) + 1e-6f);
    const float rk = rsqrtf(sk * (1.0f / 64.0f) + 1e-6f);
    const size_t ho = ((size_t)h * L_SEQ + l) * HD + lane;
    Qh[ho] = f2bf(q * rq * gqv);
    Kh[ho] = f2bf(k * rk * gkv);
    vt[wv * 16 + i][lane] = qkv[base + 2 * DIM];  // v: passthrough bf16
  }
  __syncthreads();
  const int d = tid >> 2;
  const int cb = (tid & 3) * 16;
  u16* dst = Vt + ((size_t)h * HD + d) * L_SEQ + lblk + cb;
#pragma unroll
  for (int j0 = 0; j0 < 4; j0++) {
    u16x4 o;
    o.x = vt[cb + j0 * 4 + 0][d];
    o.y = vt[cb + j0 * 4 + 1][d];
    o.z = vt[cb + j0 * 4 + 2][d];
    o.w = vt[cb + j0 * 4 + 3][d];
    *(u16x4*)(dst + j0 * 4) = o;
  }
}

// ---------------- MFMA flash, split-KV: grid (L/64, H, KVSPLIT) -------------
// Each block handles KVHALF kvs; writes unnormalized f32 O-partial + (m,l).
__global__ __launch_bounds__(256) void flash_kernel(const u16* __restrict__ Qh,
                                                    const u16* __restrict__ Kh,
                                                    const u16* __restrict__ Vt,
                                                    float* __restrict__ Op0,
                                                    float* __restrict__ Op1,
                                                    float2* __restrict__ ml) {
  const int h = blockIdx.y;
  const int qblk = blockIdx.x * 64;
  const int sp = blockIdx.z;
  const int kv0 = sp * KVHALF;
  float* Op = sp ? Op1 : Op0;
  const int tid = threadIdx.x;
  const int lane = tid & 63, wv = tid >> 6;
  __shared__ u16 Ks[64][64];     // [kv][d]
  __shared__ u16 Vs[64][64];     // [d][kv]
  __shared__ u16 Ps[4][16][64];  // per-wave [q][kv]

  const int l4 = lane & 15;
  const int kc = (lane >> 4) * 8;
  const int swz = (lane & 7) << 3;  // read-side swizzle

  const int qrow = qblk + wv * 16 + l4;
  const u16* Qp = Qh + ((size_t)h * L_SEQ + qrow) * HD;
  const bf16x8 qf0 = *(const bf16x8*)(Qp + kc);
  const bf16x8 qf1 = *(const bf16x8*)(Qp + 32 + kc);

  f32x4 oacc[4];
#pragma unroll
  for (int dt = 0; dt < 4; dt++) oacc[dt] = (f32x4)(0.0f);
  float mr[4] = {-1e30f, -1e30f, -1e30f, -1e30f};
  float lr[4] = {0.f, 0.f, 0.f, 0.f};

  const int krow = tid >> 3;
  const int kcol = (tid & 7) * 8;
  const u16* Kg = Kh + (size_t)h * L_SEQ * HD + (size_t)krow * HD + kcol;
  u16* KsW0 = &Ks[krow][kcol ^ ((krow & 7) << 3)];
  u16* KsW1 = KsW0 + 32 * 64;
  const int vd = tid >> 2;
  const int vcol = (tid & 3) * 16;
  const u16* Vg = Vt + ((size_t)h * HD + vd) * L_SEQ;
  u16* VsW0 = &Vs[vd][vcol ^ ((vd & 7) << 3)];
  u16* VsW1 = &Vs[vd][(vcol + 8) ^ ((vd & 7) << 3)];

  // prologue: first tile of this split into regs
  bf16x8 kr0 = *(const bf16x8*)(Kg + (size_t)kv0 * HD);
  bf16x8 kr1 = *(const bf16x8*)(Kg + (size_t)(kv0 + 32) * HD);
  bf16x8 vr0 = *(const bf16x8*)(Vg + kv0 + vcol);
  bf16x8 vr1 = *(const bf16x8*)(Vg + kv0 + vcol + 8);

  for (int kb = kv0; kb < kv0 + KVHALF; kb += 64) {
    __syncthreads();
    *(bf16x8*)KsW0 = kr0;
    *(bf16x8*)KsW1 = kr1;
    *(bf16x8*)VsW0 = vr0;
    *(bf16x8*)VsW1 = vr1;
    if (kb + 64 < kv0 + KVHALF) {  // T14 prefetch
      kr0 = *(const bf16x8*)(Kg + (size_t)(kb + 64) * HD);
      kr1 = *(const bf16x8*)(Kg + (size_t)(kb + 96) * HD);
      vr0 = *(const bf16x8*)(Vg + kb + 64 + vcol);
      vr1 = *(const bf16x8*)(Vg + kb + 72 + vcol);
    }
    __syncthreads();

    f32x4 s[4];
#pragma unroll
    for (int st = 0; st < 4; st++) {
      const u16* kp = &Ks[st * 16 + l4][0];
      bf16x8 ka = *(const bf16x8*)(kp + (kc ^ swz));
      bf16x8 kb2 = *(const bf16x8*)(kp + ((kc + 32) ^ swz));
      s[st] = __builtin_amdgcn_mfma_f32_16x16x32_bf16(qf0, ka, (f32x4)(0.0f), 0, 0, 0);
      s[st] = __builtin_amdgcn_mfma_f32_16x16x32_bf16(qf1, kb2, s[st], 0, 0, 0);
    }

    float scl[4];
#pragma unroll
    for (int r = 0; r < 4; r++) {
      float mx = fmaxf(fmaxf(s[0][r], s[1][r]), fmaxf(s[2][r], s[3][r]));
      mx = fmaxf(mx, __shfl_xor(mx, 1));
      mx = fmaxf(mx, __shfl_xor(mx, 2));
      mx = fmaxf(mx, __shfl_xor(mx, 4));
      mx = fmaxf(mx, __shfl_xor(mx, 8));
      const float nm = fmaxf(mr[r], mx);
      scl[r] = __builtin_amdgcn_exp2f(mr[r] - nm);  // scores in log2 domain
      mr[r] = nm;
      const float p0 = __builtin_amdgcn_exp2f(s[0][r] - nm);
      const float p1 = __builtin_amdgcn_exp2f(s[1][r] - nm);
      const float p2 = __builtin_amdgcn_exp2f(s[2][r] - nm);
      const float p3 = __builtin_amdgcn_exp2f(s[3][r] - nm);
      float sum = (p0 + p1) + (p2 + p3);
      sum += __shfl_xor(sum, 1);
      sum += __shfl_xor(sum, 2);
      sum += __shfl_xor(sum, 4);
      sum += __shfl_xor(sum, 8);
      lr[r] = lr[r] * scl[r] + sum;
      const int qr = (lane >> 4) * 4 + r;
      const int wsw = (qr & 7) << 3;
      u16* pr = &Ps[wv][qr][0];
      pr[l4 ^ wsw] = f2bf(p0);
      pr[(16 + l4) ^ wsw] = f2bf(p1);
      pr[(32 + l4) ^ wsw] = f2bf(p2);
      pr[(48 + l4) ^ wsw] = f2bf(p3);
    }
#pragma unroll
    for (int dt = 0; dt < 4; dt++)
#pragma unroll
      for (int r = 0; r < 4; r++) oacc[dt][r] *= scl[r];

    // Ps wave-private; in-wave DS ordering -> no barrier needed.
    const u16* pp = &Ps[wv][l4][0];
    bf16x8 pf0 = *(const bf16x8*)(pp + (kc ^ swz));
    bf16x8 pf1 = *(const bf16x8*)(pp + ((kc + 32) ^ swz));
#pragma unroll
    for (int dt = 0; dt < 4; dt++) {
      const u16* vp = &Vs[dt * 16 + l4][0];
      bf16x8 vf0 = *(const bf16x8*)(vp + (kc ^ swz));
      bf16x8 vf1 = *(const bf16x8*)(vp + ((kc + 32) ^ swz));
      oacc[dt] = __builtin_amdgcn_mfma_f32_16x16x32_bf16(pf0, vf0, oacc[dt], 0, 0, 0);
      oacc[dt] = __builtin_amdgcn_mfma_f32_16x16x32_bf16(pf1, vf1, oacc[dt], 0, 0, 0);
    }
  }

  // write unnormalized partials (f32) + per-row (m,l)
#pragma unroll
  for (int r = 0; r < 4; r++) {
    const int row = qblk + wv * 16 + (lane >> 4) * 4 + r;
    float* op = Op + ((size_t)h * L_SEQ + row) * HD + l4;
#pragma unroll
    for (int dt = 0; dt < 4; dt++) op[dt * 16] = oacc[dt][r];
    if (l4 == 0) {
      float2 v;
      v.x = mr[r];
      v.y = lr[r];
      ml[(size_t)sp * NH * L_SEQ + (size_t)h * L_SEQ + row] = v;
    }
  }
}

// ---------------- merge the two KV-split partials -> Ob bf16 ----------------
__global__ __launch_bounds__(256) void merge_kernel(const float* __restrict__ Op0,
                                                    const float* __restrict__ Op1,
                                                    const float2* __restrict__ ml,
                                                    u16* __restrict__ Ob) {
  const int h = blockIdx.y;
  const int row = blockIdx.x * 4 + (threadIdx.x >> 6);
  const int d = threadIdx.x & 63;
  const float2 a = ml[(size_t)h * L_SEQ + row];
  const float2 b = ml[(size_t)NH * L_SEQ + (size_t)h * L_SEQ + row];
  const float m = fmaxf(a.x, b.x);
  const float e0 = __builtin_amdgcn_exp2f(a.x - m);
  const float e1 = __builtin_amdgcn_exp2f(b.x - m);
  const float inv = 1.0f / (a.y * e0 + b.y * e1);
  const size_t idx = ((size_t)h * L_SEQ + row) * HD + d;
  const float o = (Op0[idx] * e0 + Op1[idx] * e1) * inv;
  Ob[(size_t)row * DIM + h * HD + d] = f2bf(o);
}

// ---------------- launcher ----------------
extern "C" void kernel_launch(void* const* d_in, const int* in_sizes, int n_in,
                              void* d_out, int out_size, void* d_ws, size_t ws_size,
                              hipStream_t stream) {
  const float* x = (const float*)d_in[0];
  const float* w_qkv = (const float*)d_in[1];
  const float* b_qkv = (const float*)d_in[2];
  const float* w_proj = (const float*)d_in[3];
  const float* b_proj = (const float*)d_in[4];
  const float* g_q = (const float*)d_in[5];
  const float* g_k = (const float*)d_in[6];

  char* ws = (char*)d_ws;
  u16* x_b = (u16*)(ws + 0);           // 6291456   (dead after QKV GEMM)
  u16* wqkv_b = (u16*)(ws + 6291456);  // 14155776  (dead after QKV GEMM)
  u16* wpj_b = (u16*)(ws + 20447232);  // 4718592   (live until proj)
  u16* qkv = (u16*)(ws + 25165824);    // 18874368  (dead after qkvnorm)
  u16* Qh = (u16*)(ws + 44040192);     // 6291456
  u16* Kh = (u16*)(ws + 50331648);     // 6291456
  u16* Vt = (u16*)(ws + 56623104);     // 6291456
  u16* Ob = (u16*)(ws + 62914560);     // 6291456 -> high water 69206016
  // flash-time reuse of dead regions:
  float* Op0 = (float*)(ws + 0);         // 12582912 over x_b/wqkv_b
  float2* ml = (float2*)(ws + 12582912); // 786432  (ends 13369344 < 20447232)
  float* Op1 = (float*)(ws + 25165824);  // 12582912 over qkv

  cast_kernel<<<(L_SEQ * DIM / 4 + 255) / 256, 256, 0, stream>>>(x, x_b, L_SEQ * DIM / 4);
  cast_kernel<<<(NQKV * DIM / 4 + 255) / 256, 256, 0, stream>>>(w_qkv, wqkv_b, NQKV * DIM / 4);
  cast_kernel<<<(DIM * DIM / 4 + 255) / 256, 256, 0, stream>>>(w_proj, wpj_b, DIM * DIM / 4);

  gemm_bt<1><<<(L_SEQ / 128) * (NQKV / 128), 256, 0, stream>>>(
      x_b, wqkv_b, b_qkv, (void*)qkv, L_SEQ, NQKV, DIM);

  qkvnorm_kernel<<<dim3(L_SEQ / 64, NH), 256, 0, stream>>>(qkv, g_q, g_k, Qh, Kh, Vt);

  flash_kernel<<<dim3(L_SEQ / 64, NH, KVSPLIT), 256, 0, stream>>>(Qh, Kh, Vt, Op0, Op1, ml);

  merge_kernel<<<dim3(L_SEQ / 4, NH), 256, 0, stream>>>(Op0, Op1, ml, Ob);

  // d_out is float32
  gemm_bt<0><<<(L_SEQ / 128) * (DIM / 128), 256, 0, stream>>>(
      Ob, wpj_b, b_proj, d_out, L_SEQ, DIM, DIM);
}

// Round 9
// 179.130 us; speedup vs baseline: 1.1776x; 1.1776x over previous
//
#include <hip/hip_runtime.h>
#include <stdint.h>

#define L_SEQ 2048
#define DIM 1536
#define NH 24
#define HD 64
#define NQKV 4608

typedef unsigned short u16;
typedef __attribute__((ext_vector_type(4))) float f32x4;
typedef __attribute__((ext_vector_type(8))) short bf16x8;
typedef __attribute__((ext_vector_type(4))) u16 u16x4;
typedef __attribute__((ext_vector_type(8))) u16 u16x8;

__device__ __forceinline__ u16 f2bf(float f) {
  unsigned u = __builtin_bit_cast(unsigned, f);
  u += 0x7fffu + ((u >> 16) & 1u);
  return (u16)(u >> 16);
}
__device__ __forceinline__ float b2f(u16 u) {
  return __builtin_bit_cast(float, (unsigned)u << 16);
}

__device__ __forceinline__ void gload_lds16(const void* g, void* lds) {
  __builtin_amdgcn_global_load_lds(
      (const __attribute__((address_space(1))) unsigned int*)g,
      (__attribute__((address_space(3))) unsigned int*)lds, 16, 0, 0);
}

// ---------------- cast f32 -> bf16 ----------------
__global__ __launch_bounds__(256) void cast_kernel(const float* __restrict__ in,
                                                   u16* __restrict__ out, int n4) {
  int i = blockIdx.x * 256 + threadIdx.x;
  if (i >= n4) return;
  f32x4 v = ((const f32x4*)in)[i];
  u16x4 o;
  o.x = f2bf(v.x);
  o.y = f2bf(v.y);
  o.z = f2bf(v.z);
  o.w = f2bf(v.w);
  ((u16x4*)out)[i] = o;
}

// ---------------- GEMM: C[M][N] = A[M][K] * B[N][K]^T + bias ----------------
// m97-style: 128x128 tile, BK=32, 4 waves (2x2), 16x16x32 MFMA, global_load_lds.
template <int WRITE_BF16>
__global__ __launch_bounds__(256) void gemm_bt(const u16* __restrict__ A,
                                               const u16* __restrict__ B,
                                               const float* __restrict__ bias,
                                               void* __restrict__ Cout,
                                               int M, int N, int K) {
  __shared__ u16 As[128 * 32];
  __shared__ u16 Bs[128 * 32];
  const int nb = N >> 7;
  const int bx = (int)blockIdx.x % nb;
  const int by = (int)blockIdx.x / nb;
  const int tid = threadIdx.x;
  const int lane = tid & 63;
  const int wv = tid >> 6;
  const int wr = wv >> 1, wc = wv & 1;

  f32x4 acc[4][4];
#pragma unroll
  for (int i = 0; i < 4; i++)
#pragma unroll
    for (int j = 0; j < 4; j++) acc[i][j] = (f32x4)(0.0f);

  const int e0 = tid * 8;
  const int r0 = e0 >> 5, c0 = e0 & 31;
  const u16* Ag0 = A + (size_t)(by * 128 + r0) * K + c0;
  const u16* Ag1 = A + (size_t)(by * 128 + r0 + 64) * K + c0;
  const u16* Bg0 = B + (size_t)(bx * 128 + r0) * K + c0;
  const u16* Bg1 = B + (size_t)(bx * 128 + r0 + 64) * K + c0;
  char* AsB = (char*)As + wv * 1024;  // wave-uniform LDS base (+ lane*16 by HW)
  char* BsB = (char*)Bs + wv * 1024;
  const int kc = (lane >> 4) * 8;

  for (int k0 = 0; k0 < K; k0 += 32) {
    __syncthreads();
    gload_lds16(Ag0 + k0, AsB);
    gload_lds16(Ag1 + k0, AsB + 4096);
    gload_lds16(Bg0 + k0, BsB);
    gload_lds16(Bg1 + k0, BsB + 4096);
    __syncthreads();

    bf16x8 af[4], bfr[4];
#pragma unroll
    for (int mt = 0; mt < 4; mt++)
      af[mt] = *(const bf16x8*)&As[(wr * 64 + mt * 16 + (lane & 15)) * 32 + kc];
#pragma unroll
    for (int nt = 0; nt < 4; nt++)
      bfr[nt] = *(const bf16x8*)&Bs[(wc * 64 + nt * 16 + (lane & 15)) * 32 + kc];
#pragma unroll
    for (int mt = 0; mt < 4; mt++)
#pragma unroll
      for (int nt = 0; nt < 4; nt++)
        acc[mt][nt] = __builtin_amdgcn_mfma_f32_16x16x32_bf16(af[mt], bfr[nt],
                                                              acc[mt][nt], 0, 0, 0);
  }

  // C/D layout: col = lane&15, row = (lane>>4)*4 + reg
  const int colb = bx * 128 + wc * 64 + (lane & 15);
  const int rowb = by * 128 + wr * 64 + ((lane >> 4) << 2);
#pragma unroll
  for (int nt = 0; nt < 4; nt++) {
    const int col = colb + nt * 16;
    const float bv = bias[col];
#pragma unroll
    for (int mt = 0; mt < 4; mt++) {
#pragma unroll
      for (int r = 0; r < 4; r++) {
        const int row = rowb + mt * 16 + r;
        float v = acc[mt][nt][r] + bv;
        if (WRITE_BF16)
          ((u16*)Cout)[(size_t)row * N + col] = f2bf(v);
        else
          ((float*)Cout)[(size_t)row * N + col] = v;
      }
    }
  }
}

// ---------------- QK-RMSNorm + layout rearrange (bf16 qkv input) ------------
// Q additionally scaled by log2(e)/8 so attention scores are in log2 domain.
__global__ __launch_bounds__(256) void qkvnorm_kernel(const u16* __restrict__ qkv,
                                                      const float* __restrict__ gq,
                                                      const float* __restrict__ gk,
                                                      u16* __restrict__ Qh,
                                                      u16* __restrict__ Kh,
                                                      u16* __restrict__ Vt) {
  const int h = blockIdx.y;
  const int lblk = blockIdx.x * 64;
  const int tid = threadIdx.x;
  const int lane = tid & 63, wv = tid >> 6;
  __shared__ u16 vt[64][64];
  const float gqv = gq[lane] * 0.125f * 1.44269504088896f;  // 1/sqrt(HD) * log2(e)
  const float gkv = gk[lane];
#pragma unroll 1
  for (int i = 0; i < 16; i++) {
    const int l = lblk + wv * 16 + i;
    const size_t base = (size_t)l * NQKV + h * HD + lane;
    const float q = b2f(qkv[base]);
    const float k = b2f(qkv[base + DIM]);
    float sq = q * q, sk = k * k;
#pragma unroll
    for (int m = 32; m; m >>= 1) {
      sq += __shfl_xor(sq, m);
      sk += __shfl_xor(sk, m);
    }
    const float rq = rsqrtf(sq * (1.0f / 64.0f) + 1e-6f);
    const float rk = rsqrtf(sk * (1.0f / 64.0f) + 1e-6f);
    const size_t ho = ((size_t)h * L_SEQ + l) * HD + lane;
    Qh[ho] = f2bf(q * rq * gqv);
    Kh[ho] = f2bf(k * rk * gkv);
    vt[wv * 16 + i][lane] = qkv[base + 2 * DIM];  // v: passthrough bf16
  }
  __syncthreads();
  const int d = tid >> 2;
  const int cb = (tid & 3) * 16;
  u16* dst = Vt + ((size_t)h * HD + d) * L_SEQ + lblk + cb;
#pragma unroll
  for (int j0 = 0; j0 < 4; j0++) {
    u16x4 o;
    o.x = vt[cb + j0 * 4 + 0][d];
    o.y = vt[cb + j0 * 4 + 1][d];
    o.z = vt[cb + j0 * 4 + 2][d];
    o.w = vt[cb + j0 * 4 + 3][d];
    *(u16x4*)(dst + j0 * 4) = o;
  }
}

// ---------------- MFMA flash, KVBLK=64, wave-max + MFMA row-sums ------------
// grid (L/64, H), 4 waves x 16 q-rows. Softmax: single wave-uniform running max
// (6 shuffles/tile); per-row l via ones-B-fragment MFMA (0 shuffles).
__global__ __launch_bounds__(256) void flash_kernel(const u16* __restrict__ Qh,
                                                    const u16* __restrict__ Kh,
                                                    const u16* __restrict__ Vt,
                                                    u16* __restrict__ O) {
  const int h = blockIdx.y;
  const int qblk = blockIdx.x * 64;
  const int tid = threadIdx.x;
  const int lane = tid & 63, wv = tid >> 6;
  __shared__ u16 Ks[64][64];     // [kv][d]
  __shared__ u16 Vs[64][64];     // [d][kv]
  __shared__ u16 Ps[4][16][64];  // per-wave [q][kv]

  const int l4 = lane & 15;
  const int kc = (lane >> 4) * 8;
  const int swz = (lane & 7) << 3;  // read-side swizzle

  const int qrow = qblk + wv * 16 + l4;
  const u16* Qp = Qh + ((size_t)h * L_SEQ + qrow) * HD;
  const bf16x8 qf0 = *(const bf16x8*)(Qp + kc);
  const bf16x8 qf1 = *(const bf16x8*)(Qp + 32 + kc);
  const bf16x8 ones = (bf16x8)(short)0x3F80;  // bf16 1.0 splat

  f32x4 oacc[4];
#pragma unroll
  for (int dt = 0; dt < 4; dt++) oacc[dt] = (f32x4)(0.0f);
  float mr = -1e30f;                  // wave-uniform running max (log2 domain)
  float lr[4] = {0.f, 0.f, 0.f, 0.f}; // per-q-row running denom

  const int krow = tid >> 3;
  const int kcol = (tid & 7) * 8;
  const u16* Kg = Kh + (size_t)h * L_SEQ * HD + (size_t)krow * HD + kcol;
  u16* KsW0 = &Ks[krow][kcol ^ ((krow & 7) << 3)];
  u16* KsW1 = KsW0 + 32 * 64;
  const int vd = tid >> 2;
  const int vcol = (tid & 3) * 16;
  const u16* Vg = Vt + ((size_t)h * HD + vd) * L_SEQ;
  u16* VsW0 = &Vs[vd][vcol ^ ((vd & 7) << 3)];
  u16* VsW1 = &Vs[vd][(vcol + 8) ^ ((vd & 7) << 3)];

  bf16x8 kr0 = *(const bf16x8*)(Kg);
  bf16x8 kr1 = *(const bf16x8*)(Kg + 32 * HD);
  bf16x8 vr0 = *(const bf16x8*)(Vg + vcol);
  bf16x8 vr1 = *(const bf16x8*)(Vg + vcol + 8);

  for (int kb = 0; kb < L_SEQ; kb += 64) {
    __syncthreads();
    *(bf16x8*)KsW0 = kr0;
    *(bf16x8*)KsW1 = kr1;
    *(bf16x8*)VsW0 = vr0;
    *(bf16x8*)VsW1 = vr1;
    if (kb + 64 < L_SEQ) {  // T14 prefetch
      kr0 = *(const bf16x8*)(Kg + (size_t)(kb + 64) * HD);
      kr1 = *(const bf16x8*)(Kg + (size_t)(kb + 96) * HD);
      vr0 = *(const bf16x8*)(Vg + kb + 64 + vcol);
      vr1 = *(const bf16x8*)(Vg + kb + 72 + vcol);
    }
    __syncthreads();

    f32x4 s[4];
    __builtin_amdgcn_s_setprio(1);
#pragma unroll
    for (int st = 0; st < 4; st++) {
      const u16* kp = &Ks[st * 16 + l4][0];
      bf16x8 ka = *(const bf16x8*)(kp + (kc ^ swz));
      bf16x8 kb2 = *(const bf16x8*)(kp + ((kc + 32) ^ swz));
      s[st] = __builtin_amdgcn_mfma_f32_16x16x32_bf16(qf0, ka, (f32x4)(0.0f), 0, 0, 0);
      s[st] = __builtin_amdgcn_mfma_f32_16x16x32_bf16(qf1, kb2, s[st], 0, 0, 0);
    }
    __builtin_amdgcn_s_setprio(0);

    // wave-uniform max: in-lane tree over 16 regs, then 6-level shuffle
    float mx;
    {
      float a0 = fmaxf(fmaxf(s[0][0], s[0][1]), fmaxf(s[0][2], s[0][3]));
      float a1 = fmaxf(fmaxf(s[1][0], s[1][1]), fmaxf(s[1][2], s[1][3]));
      float a2 = fmaxf(fmaxf(s[2][0], s[2][1]), fmaxf(s[2][2], s[2][3]));
      float a3 = fmaxf(fmaxf(s[3][0], s[3][1]), fmaxf(s[3][2], s[3][3]));
      mx = fmaxf(fmaxf(a0, a1), fmaxf(a2, a3));
      mx = fmaxf(mx, __shfl_xor(mx, 1));
      mx = fmaxf(mx, __shfl_xor(mx, 2));
      mx = fmaxf(mx, __shfl_xor(mx, 4));
      mx = fmaxf(mx, __shfl_xor(mx, 8));
      mx = fmaxf(mx, __shfl_xor(mx, 16));
      mx = fmaxf(mx, __shfl_xor(mx, 32));
    }
    if (mx > mr) {  // wave-uniform branch: rescale only when max grows
      const float scl = __builtin_amdgcn_exp2f(mr - mx);
      mr = mx;
#pragma unroll
      for (int r = 0; r < 4; r++) lr[r] *= scl;
#pragma unroll
      for (int dt = 0; dt < 4; dt++)
#pragma unroll
        for (int r = 0; r < 4; r++) oacc[dt][r] *= scl;
    }

    // P = exp2(s - mr), write to wave-private Ps
#pragma unroll
    for (int r = 0; r < 4; r++) {
      const int qr = (lane >> 4) * 4 + r;
      const int wsw = (qr & 7) << 3;
      u16* pr = &Ps[wv][qr][0];
      pr[l4 ^ wsw] = f2bf(__builtin_amdgcn_exp2f(s[0][r] - mr));
      pr[(16 + l4) ^ wsw] = f2bf(__builtin_amdgcn_exp2f(s[1][r] - mr));
      pr[(32 + l4) ^ wsw] = f2bf(__builtin_amdgcn_exp2f(s[2][r] - mr));
      pr[(48 + l4) ^ wsw] = f2bf(__builtin_amdgcn_exp2f(s[3][r] - mr));
    }

    // Ps wave-private; in-wave DS ordering -> no barrier needed.
    const u16* pp = &Ps[wv][l4][0];
    bf16x8 pf0 = *(const bf16x8*)(pp + (kc ^ swz));
    bf16x8 pf1 = *(const bf16x8*)(pp + ((kc + 32) ^ swz));
    __builtin_amdgcn_s_setprio(1);
    f32x4 ls = __builtin_amdgcn_mfma_f32_16x16x32_bf16(pf0, ones, (f32x4)(0.0f), 0, 0, 0);
    ls = __builtin_amdgcn_mfma_f32_16x16x32_bf16(pf1, ones, ls, 0, 0, 0);
#pragma unroll
    for (int dt = 0; dt < 4; dt++) {
      const u16* vp = &Vs[dt * 16 + l4][0];
      bf16x8 vf0 = *(const bf16x8*)(vp + (kc ^ swz));
      bf16x8 vf1 = *(const bf16x8*)(vp + ((kc + 32) ^ swz));
      oacc[dt] = __builtin_amdgcn_mfma_f32_16x16x32_bf16(pf0, vf0, oacc[dt], 0, 0, 0);
      oacc[dt] = __builtin_amdgcn_mfma_f32_16x16x32_bf16(pf1, vf1, oacc[dt], 0, 0, 0);
    }
    __builtin_amdgcn_s_setprio(0);
#pragma unroll
    for (int r = 0; r < 4; r++) lr[r] += ls[r];  // per-row denom, no shuffles
  }

#pragma unroll
  for (int r = 0; r < 4; r++) {
    const float inv = 1.0f / lr[r];
    const int row = qblk + wv * 16 + (lane >> 4) * 4 + r;
#pragma unroll
    for (int dt = 0; dt < 4; dt++) {
      const int col = h * HD + dt * 16 + l4;
      O[(size_t)row * DIM + col] = f2bf(oacc[dt][r] * inv);
    }
  }
}

// ---------------- launcher ----------------
extern "C" void kernel_launch(void* const* d_in, const int* in_sizes, int n_in,
                              void* d_out, int out_size, void* d_ws, size_t ws_size,
                              hipStream_t stream) {
  const float* x = (const float*)d_in[0];
  const float* w_qkv = (const float*)d_in[1];
  const float* b_qkv = (const float*)d_in[2];
  const float* w_proj = (const float*)d_in[3];
  const float* b_proj = (const float*)d_in[4];
  const float* g_q = (const float*)d_in[5];
  const float* g_k = (const float*)d_in[6];

  char* ws = (char*)d_ws;
  u16* x_b = (u16*)(ws + 0);           // 6291456
  u16* wqkv_b = (u16*)(ws + 6291456);  // 14155776
  u16* wpj_b = (u16*)(ws + 20447232);  // 4718592
  u16* qkv = (u16*)(ws + 25165824);    // 18874368
  u16* Qh = (u16*)(ws + 44040192);     // 6291456
  u16* Kh = (u16*)(ws + 50331648);     // 6291456
  u16* Vt = (u16*)(ws + 56623104);     // 6291456
  u16* Ob = (u16*)(ws + 62914560);     // 6291456 -> total 69206016

  cast_kernel<<<(L_SEQ * DIM / 4 + 255) / 256, 256, 0, stream>>>(x, x_b, L_SEQ * DIM / 4);
  cast_kernel<<<(NQKV * DIM / 4 + 255) / 256, 256, 0, stream>>>(w_qkv, wqkv_b, NQKV * DIM / 4);
  cast_kernel<<<(DIM * DIM / 4 + 255) / 256, 256, 0, stream>>>(w_proj, wpj_b, DIM * DIM / 4);

  gemm_bt<1><<<(L_SEQ / 128) * (NQKV / 128), 256, 0, stream>>>(
      x_b, wqkv_b, b_qkv, (void*)qkv, L_SEQ, NQKV, DIM);

  qkvnorm_kernel<<<dim3(L_SEQ / 64, NH), 256, 0, stream>>>(qkv, g_q, g_k, Qh, Kh, Vt);

  flash_kernel<<<dim3(L_SEQ / 64, NH), 256, 0, stream>>>(Qh, Kh, Vt, Ob);

  // d_out is float32
  gemm_bt<0><<<(L_SEQ / 128) * (DIM / 128), 256, 0, stream>>>(
      Ob, wpj_b, b_proj, d_out, L_SEQ, DIM, DIM);
}

// Round 10
// 157.683 us; speedup vs baseline: 1.3378x; 1.1360x over previous
//
#include <hip/hip_runtime.h>
#include <stdint.h>

#define L_SEQ 2048
#define DIM 1536
#define NH 24
#define HD 64
#define NQKV 4608

typedef unsigned short u16;
typedef __attribute__((ext_vector_type(4))) float f32x4;
typedef __attribute__((ext_vector_type(8))) short bf16x8;
typedef __attribute__((ext_vector_type(4))) u16 u16x4;
typedef __attribute__((ext_vector_type(8))) u16 u16x8;

__device__ __forceinline__ u16 f2bf(float f) {
  unsigned u = __builtin_bit_cast(unsigned, f);
  u += 0x7fffu + ((u >> 16) & 1u);
  return (u16)(u >> 16);
}
__device__ __forceinline__ float b2f(u16 u) {
  return __builtin_bit_cast(float, (unsigned)u << 16);
}

__device__ __forceinline__ void gload_lds16(const void* g, void* lds) {
  __builtin_amdgcn_global_load_lds(
      (const __attribute__((address_space(1))) unsigned int*)g,
      (__attribute__((address_space(3))) unsigned int*)lds, 16, 0, 0);
}

// ---------------- fused cast f32 -> bf16 for x, w_qkv, w_proj ----------------
// dsts are contiguous in ws: [x_b | wqkv_b | wpj_b]
__global__ __launch_bounds__(256) void cast3_kernel(const float* __restrict__ x,
                                                    const float* __restrict__ wq,
                                                    const float* __restrict__ wp,
                                                    u16* __restrict__ out) {
  const int n1 = (L_SEQ * DIM) / 4;          // 786432
  const int n2 = (NQKV * DIM) / 4;           // 1769472
  const int n3 = (DIM * DIM) / 4;            // 589824
  const int tot = n1 + n2 + n3;
  for (int i = blockIdx.x * 256 + threadIdx.x; i < tot; i += gridDim.x * 256) {
    const f32x4* src;
    int j;
    if (i < n1) {
      src = (const f32x4*)x;
      j = i;
    } else if (i < n1 + n2) {
      src = (const f32x4*)wq;
      j = i - n1;
    } else {
      src = (const f32x4*)wp;
      j = i - n1 - n2;
    }
    f32x4 v = src[j];
    u16x4 o;
    o.x = f2bf(v.x);
    o.y = f2bf(v.y);
    o.z = f2bf(v.z);
    o.w = f2bf(v.w);
    ((u16x4*)out)[i] = o;
  }
}

// ---------------- GEMM: C[M][N] = A[M][K] * B[N][K]^T + bias ----------------
// 128x128 tile, BK=32, 4 waves, 16x16x32 MFMA, global_load_lds,
// 2-phase double-buffered (T3-minimal): stage t+1 before compute t, 1 barrier/iter.
template <int WRITE_BF16>
__global__ __launch_bounds__(256) void gemm_bt(const u16* __restrict__ A,
                                               const u16* __restrict__ B,
                                               const float* __restrict__ bias,
                                               void* __restrict__ Cout,
                                               int M, int N, int K) {
  __shared__ u16 As[2][128 * 32];
  __shared__ u16 Bs[2][128 * 32];
  const int nb = N >> 7;
  const int bx = (int)blockIdx.x % nb;
  const int by = (int)blockIdx.x / nb;
  const int tid = threadIdx.x;
  const int lane = tid & 63;
  const int wv = tid >> 6;
  const int wr = wv >> 1, wc = wv & 1;

  f32x4 acc[4][4];
#pragma unroll
  for (int i = 0; i < 4; i++)
#pragma unroll
    for (int j = 0; j < 4; j++) acc[i][j] = (f32x4)(0.0f);

  const int e0 = tid * 8;
  const int r0 = e0 >> 5, c0 = e0 & 31;
  const u16* Ag0 = A + (size_t)(by * 128 + r0) * K + c0;
  const u16* Ag1 = A + (size_t)(by * 128 + r0 + 64) * K + c0;
  const u16* Bg0 = B + (size_t)(bx * 128 + r0) * K + c0;
  const u16* Bg1 = B + (size_t)(bx * 128 + r0 + 64) * K + c0;
  const int kc = (lane >> 4) * 8;
  const int wb = wv * 1024;  // wave-uniform LDS byte base within a rep

  // prologue: stage tile 0 into buf 0
  gload_lds16(Ag0, (char*)As[0] + wb);
  gload_lds16(Ag1, (char*)As[0] + wb + 4096);
  gload_lds16(Bg0, (char*)Bs[0] + wb);
  gload_lds16(Bg1, (char*)Bs[0] + wb + 4096);
  __syncthreads();

  int cur = 0;
  for (int k0 = 0; k0 < K; k0 += 32) {
    const int nxt = cur ^ 1;
    if (k0 + 32 < K) {  // stage next tile; latency hidden under this tile's MFMAs
      gload_lds16(Ag0 + k0 + 32, (char*)As[nxt] + wb);
      gload_lds16(Ag1 + k0 + 32, (char*)As[nxt] + wb + 4096);
      gload_lds16(Bg0 + k0 + 32, (char*)Bs[nxt] + wb);
      gload_lds16(Bg1 + k0 + 32, (char*)Bs[nxt] + wb + 4096);
    }
    const u16* Asc = As[cur];
    const u16* Bsc = Bs[cur];
    bf16x8 af[4], bfr[4];
#pragma unroll
    for (int mt = 0; mt < 4; mt++)
      af[mt] = *(const bf16x8*)&Asc[(wr * 64 + mt * 16 + (lane & 15)) * 32 + kc];
#pragma unroll
    for (int nt = 0; nt < 4; nt++)
      bfr[nt] = *(const bf16x8*)&Bsc[(wc * 64 + nt * 16 + (lane & 15)) * 32 + kc];
#pragma unroll
    for (int mt = 0; mt < 4; mt++)
#pragma unroll
      for (int nt = 0; nt < 4; nt++)
        acc[mt][nt] = __builtin_amdgcn_mfma_f32_16x16x32_bf16(af[mt], bfr[nt],
                                                              acc[mt][nt], 0, 0, 0);
    __syncthreads();  // drains prefetch vmcnt + guards buf reuse
    cur = nxt;
  }

  // C/D layout: col = lane&15, row = (lane>>4)*4 + reg
  const int colb = bx * 128 + wc * 64 + (lane & 15);
  const int rowb = by * 128 + wr * 64 + ((lane >> 4) << 2);
#pragma unroll
  for (int nt = 0; nt < 4; nt++) {
    const int col = colb + nt * 16;
    const float bv = bias[col];
#pragma unroll
    for (int mt = 0; mt < 4; mt++) {
#pragma unroll
      for (int r = 0; r < 4; r++) {
        const int row = rowb + mt * 16 + r;
        float v = acc[mt][nt][r] + bv;
        if (WRITE_BF16)
          ((u16*)Cout)[(size_t)row * N + col] = f2bf(v);
        else
          ((float*)Cout)[(size_t)row * N + col] = v;
      }
    }
  }
}

// ---------------- QK-RMSNorm + layout rearrange (bf16 qkv input) ------------
// Q additionally scaled by log2(e)/8 so attention scores are in log2 domain.
__global__ __launch_bounds__(256) void qkvnorm_kernel(const u16* __restrict__ qkv,
                                                      const float* __restrict__ gq,
                                                      const float* __restrict__ gk,
                                                      u16* __restrict__ Qh,
                                                      u16* __restrict__ Kh,
                                                      u16* __restrict__ Vt) {
  const int h = blockIdx.y;
  const int lblk = blockIdx.x * 64;
  const int tid = threadIdx.x;
  const int lane = tid & 63, wv = tid >> 6;
  __shared__ u16 vt[64][64];
  const float gqv = gq[lane] * 0.125f * 1.44269504088896f;  // 1/sqrt(HD) * log2(e)
  const float gkv = gk[lane];
#pragma unroll 1
  for (int i = 0; i < 16; i++) {
    const int l = lblk + wv * 16 + i;
    const size_t base = (size_t)l * NQKV + h * HD + lane;
    const float q = b2f(qkv[base]);
    const float k = b2f(qkv[base + DIM]);
    float sq = q * q, sk = k * k;
#pragma unroll
    for (int m = 32; m; m >>= 1) {
      sq += __shfl_xor(sq, m);
      sk += __shfl_xor(sk, m);
    }
    const float rq = rsqrtf(sq * (1.0f / 64.0f) + 1e-6f);
    const float rk = rsqrtf(sk * (1.0f / 64.0f) + 1e-6f);
    const size_t ho = ((size_t)h * L_SEQ + l) * HD + lane;
    Qh[ho] = f2bf(q * rq * gqv);
    Kh[ho] = f2bf(k * rk * gkv);
    vt[wv * 16 + i][lane] = qkv[base + 2 * DIM];  // v: passthrough bf16
  }
  __syncthreads();
  const int d = tid >> 2;
  const int cb = (tid & 3) * 16;
  u16* dst = Vt + ((size_t)h * HD + d) * L_SEQ + lblk + cb;
#pragma unroll
  for (int j0 = 0; j0 < 4; j0++) {
    u16x4 o;
    o.x = vt[cb + j0 * 4 + 0][d];
    o.y = vt[cb + j0 * 4 + 1][d];
    o.z = vt[cb + j0 * 4 + 2][d];
    o.w = vt[cb + j0 * 4 + 3][d];
    *(u16x4*)(dst + j0 * 4) = o;
  }
}

// ---------------- MFMA flash, swapped-QK^T softmax ---------------------------
// s[st] = mfma(K,Q) -> lane holds S^T[kv=16st+4g+r][q=l4]: per-ROW softmax with
// 2 shuffles; P written as 4x ds_write_b64; PV and ones-MFMA row-sums unchanged.
__global__ __launch_bounds__(256) void flash_kernel(const u16* __restrict__ Qh,
                                                    const u16* __restrict__ Kh,
                                                    const u16* __restrict__ Vt,
                                                    u16* __restrict__ O) {
  const int h = blockIdx.y;
  const int qblk = blockIdx.x * 64;
  const int tid = threadIdx.x;
  const int lane = tid & 63, wv = tid >> 6;
  __shared__ u16 Ks[64][64];     // [kv][d]
  __shared__ u16 Vs[64][64];     // [d][kv]
  __shared__ u16 Ps[4][16][64];  // per-wave [q][kv]

  const int l4 = lane & 15;
  const int g = lane >> 4;
  const int kc = g * 8;
  const int swz = (l4 & 7) << 3;  // row-determined swizzle (row ≡ l4 mod 8 everywhere)

  const int qrow = qblk + wv * 16 + l4;
  const u16* Qp = Qh + ((size_t)h * L_SEQ + qrow) * HD;
  const bf16x8 qf0 = *(const bf16x8*)(Qp + kc);
  const bf16x8 qf1 = *(const bf16x8*)(Qp + 32 + kc);
  const bf16x8 ones = (bf16x8)(short)0x3F80;  // bf16 1.0 splat

  f32x4 oacc[4];
#pragma unroll
  for (int dt = 0; dt < 4; dt++) oacc[dt] = (f32x4)(0.0f);
  float mr = -1e30f;                   // running max for OWN q-row (q = l4)
  float lr[4] = {0.f, 0.f, 0.f, 0.f};  // denom for oacc rows (q = g*4+r)

  const int krow = tid >> 3;
  const int kcol = (tid & 7) * 8;
  const u16* Kg = Kh + (size_t)h * L_SEQ * HD + (size_t)krow * HD + kcol;
  u16* KsW0 = &Ks[krow][kcol ^ ((krow & 7) << 3)];
  u16* KsW1 = KsW0 + 32 * 64;
  const int vd = tid >> 2;
  const int vcol = (tid & 3) * 16;
  const u16* Vg = Vt + ((size_t)h * HD + vd) * L_SEQ;
  u16* VsW0 = &Vs[vd][vcol ^ ((vd & 7) << 3)];
  u16* VsW1 = &Vs[vd][(vcol + 8) ^ ((vd & 7) << 3)];

  bf16x8 kr0 = *(const bf16x8*)(Kg);
  bf16x8 kr1 = *(const bf16x8*)(Kg + 32 * HD);
  bf16x8 vr0 = *(const bf16x8*)(Vg + vcol);
  bf16x8 vr1 = *(const bf16x8*)(Vg + vcol + 8);

  for (int kb = 0; kb < L_SEQ; kb += 64) {
    __syncthreads();
    *(bf16x8*)KsW0 = kr0;
    *(bf16x8*)KsW1 = kr1;
    *(bf16x8*)VsW0 = vr0;
    *(bf16x8*)VsW1 = vr1;
    if (kb + 64 < L_SEQ) {  // T14 prefetch
      kr0 = *(const bf16x8*)(Kg + (size_t)(kb + 64) * HD);
      kr1 = *(const bf16x8*)(Kg + (size_t)(kb + 96) * HD);
      vr0 = *(const bf16x8*)(Vg + kb + 64 + vcol);
      vr1 = *(const bf16x8*)(Vg + kb + 72 + vcol);
    }
    __syncthreads();

    // QK^T swapped: s[st] = K_st * Q -> S^T
    f32x4 s[4];
    __builtin_amdgcn_s_setprio(1);
#pragma unroll
    for (int st = 0; st < 4; st++) {
      const u16* kp = &Ks[st * 16 + l4][0];
      bf16x8 ka = *(const bf16x8*)(kp + (kc ^ swz));
      bf16x8 kb2 = *(const bf16x8*)(kp + ((kc + 32) ^ swz));
      s[st] = __builtin_amdgcn_mfma_f32_16x16x32_bf16(ka, qf0, (f32x4)(0.0f), 0, 0, 0);
      s[st] = __builtin_amdgcn_mfma_f32_16x16x32_bf16(kb2, qf1, s[st], 0, 0, 0);
    }
    __builtin_amdgcn_s_setprio(0);

    // per-row max (q = l4): in-lane 15-fmax tree + 2 shuffles across g-groups
    float mx;
    {
      float a0 = fmaxf(fmaxf(s[0][0], s[0][1]), fmaxf(s[0][2], s[0][3]));
      float a1 = fmaxf(fmaxf(s[1][0], s[1][1]), fmaxf(s[1][2], s[1][3]));
      float a2 = fmaxf(fmaxf(s[2][0], s[2][1]), fmaxf(s[2][2], s[2][3]));
      float a3 = fmaxf(fmaxf(s[3][0], s[3][1]), fmaxf(s[3][2], s[3][3]));
      mx = fmaxf(fmaxf(a0, a1), fmaxf(a2, a3));
      mx = fmaxf(mx, __shfl_xor(mx, 16));
      mx = fmaxf(mx, __shfl_xor(mx, 32));
    }
    // defer-max (T13, THR=8 in log2 domain: P bounded by 2^8)
    if (__any(mx > mr + 8.0f)) {
      const float nm = fmaxf(mr, mx);
      const float sclo = __builtin_amdgcn_exp2f(mr - nm);  // own-row (q=l4) factor
      mr = nm;
      float scl[4];
#pragma unroll
      for (int r = 0; r < 4; r++) scl[r] = __shfl(sclo, g * 4 + r);  // for q=g*4+r
#pragma unroll
      for (int r = 0; r < 4; r++) lr[r] *= scl[r];
#pragma unroll
      for (int dt = 0; dt < 4; dt++)
#pragma unroll
        for (int r = 0; r < 4; r++) oacc[dt][r] *= scl[r];
    }

    // P = exp2(s - mr) for q=l4, kv=16st+4g+r; 4x b64 packed writes
    u16* pr = &Ps[wv][l4][0];
#pragma unroll
    for (int st = 0; st < 4; st++) {
      u16x4 pw;
      pw.x = f2bf(__builtin_amdgcn_exp2f(s[st][0] - mr));
      pw.y = f2bf(__builtin_amdgcn_exp2f(s[st][1] - mr));
      pw.z = f2bf(__builtin_amdgcn_exp2f(s[st][2] - mr));
      pw.w = f2bf(__builtin_amdgcn_exp2f(s[st][3] - mr));
      *(u16x4*)(pr + ((st * 16 + g * 4) ^ swz)) = pw;
    }

    // PV + ones-MFMA row sums (Ps wave-private; in-wave DS ordering)
    const u16* pp = &Ps[wv][l4][0];
    bf16x8 pf0 = *(const bf16x8*)(pp + (kc ^ swz));
    bf16x8 pf1 = *(const bf16x8*)(pp + ((kc + 32) ^ swz));
    __builtin_amdgcn_s_setprio(1);
    f32x4 ls = __builtin_amdgcn_mfma_f32_16x16x32_bf16(pf0, ones, (f32x4)(0.0f), 0, 0, 0);
    ls = __builtin_amdgcn_mfma_f32_16x16x32_bf16(pf1, ones, ls, 0, 0, 0);
#pragma unroll
    for (int dt = 0; dt < 4; dt++) {
      const u16* vp = &Vs[dt * 16 + l4][0];
      bf16x8 vf0 = *(const bf16x8*)(vp + (kc ^ swz));
      bf16x8 vf1 = *(const bf16x8*)(vp + ((kc + 32) ^ swz));
      oacc[dt] = __builtin_amdgcn_mfma_f32_16x16x32_bf16(pf0, vf0, oacc[dt], 0, 0, 0);
      oacc[dt] = __builtin_amdgcn_mfma_f32_16x16x32_bf16(pf1, vf1, oacc[dt], 0, 0, 0);
    }
    __builtin_amdgcn_s_setprio(0);
#pragma unroll
    for (int r = 0; r < 4; r++) lr[r] += ls[r];
  }

#pragma unroll
  for (int r = 0; r < 4; r++) {
    const float inv = 1.0f / lr[r];
    const int row = qblk + wv * 16 + g * 4 + r;
#pragma unroll
    for (int dt = 0; dt < 4; dt++) {
      const int col = h * HD + dt * 16 + l4;
      O[(size_t)row * DIM + col] = f2bf(oacc[dt][r] * inv);
    }
  }
}

// ---------------- launcher ----------------
extern "C" void kernel_launch(void* const* d_in, const int* in_sizes, int n_in,
                              void* d_out, int out_size, void* d_ws, size_t ws_size,
                              hipStream_t stream) {
  const float* x = (const float*)d_in[0];
  const float* w_qkv = (const float*)d_in[1];
  const float* b_qkv = (const float*)d_in[2];
  const float* w_proj = (const float*)d_in[3];
  const float* b_proj = (const float*)d_in[4];
  const float* g_q = (const float*)d_in[5];
  const float* g_k = (const float*)d_in[6];

  char* ws = (char*)d_ws;
  u16* x_b = (u16*)(ws + 0);           // 6291456
  u16* wqkv_b = (u16*)(ws + 6291456);  // 14155776
  u16* wpj_b = (u16*)(ws + 20447232);  // 4718592
  u16* qkv = (u16*)(ws + 25165824);    // 18874368
  u16* Qh = (u16*)(ws + 44040192);     // 6291456
  u16* Kh = (u16*)(ws + 50331648);     // 6291456
  u16* Vt = (u16*)(ws + 56623104);     // 6291456
  u16* Ob = (u16*)(ws + 62914560);     // 6291456 -> total 69206016

  cast3_kernel<<<3072, 256, 0, stream>>>(x, w_qkv, w_proj, x_b);

  gemm_bt<1><<<(L_SEQ / 128) * (NQKV / 128), 256, 0, stream>>>(
      x_b, wqkv_b, b_qkv, (void*)qkv, L_SEQ, NQKV, DIM);

  qkvnorm_kernel<<<dim3(L_SEQ / 64, NH), 256, 0, stream>>>(qkv, g_q, g_k, Qh, Kh, Vt);

  flash_kernel<<<dim3(L_SEQ / 64, NH), 256, 0, stream>>>(Qh, Kh, Vt, Ob);

  // d_out is float32
  gemm_bt<0><<<(L_SEQ / 128) * (DIM / 128), 256, 0, stream>>>(
      Ob, wpj_b, b_proj, d_out, L_SEQ, DIM, DIM);
}

// Round 11
// 154.414 us; speedup vs baseline: 1.3661x; 1.0212x over previous
//
#include <hip/hip_runtime.h>
#include <stdint.h>

#define L_SEQ 2048
#define DIM 1536
#define NH 24
#define HD 64
#define NQKV 4608

typedef unsigned short u16;
typedef __attribute__((ext_vector_type(4))) float f32x4;
typedef __attribute__((ext_vector_type(8))) short bf16x8;
typedef __attribute__((ext_vector_type(4))) u16 u16x4;
typedef __attribute__((ext_vector_type(8))) u16 u16x8;

__device__ __forceinline__ u16 f2bf(float f) {
  unsigned u = __builtin_bit_cast(unsigned, f);
  u += 0x7fffu + ((u >> 16) & 1u);
  return (u16)(u >> 16);
}
__device__ __forceinline__ float b2f(u16 u) {
  return __builtin_bit_cast(float, (unsigned)u << 16);
}
// packed RNE bf16 pair: low u16 = bf16(lo), high u16 = bf16(hi)
__device__ __forceinline__ unsigned cvt_pk_bf16(float lo, float hi) {
  unsigned r;
  asm("v_cvt_pk_bf16_f32 %0, %1, %2" : "=v"(r) : "v"(lo), "v"(hi));
  return r;
}

__device__ __forceinline__ void gload_lds16(const void* g, void* lds) {
  __builtin_amdgcn_global_load_lds(
      (const __attribute__((address_space(1))) unsigned int*)g,
      (__attribute__((address_space(3))) unsigned int*)lds, 16, 0, 0);
}

// ---------------- fused cast f32 -> bf16 for x, w_qkv, w_proj ----------------
__global__ __launch_bounds__(256) void cast3_kernel(const float* __restrict__ x,
                                                    const float* __restrict__ wq,
                                                    const float* __restrict__ wp,
                                                    u16* __restrict__ out) {
  const int n1 = (L_SEQ * DIM) / 4;
  const int n2 = (NQKV * DIM) / 4;
  const int n3 = (DIM * DIM) / 4;
  const int tot = n1 + n2 + n3;
  for (int i = blockIdx.x * 256 + threadIdx.x; i < tot; i += gridDim.x * 256) {
    const f32x4* src;
    int j;
    if (i < n1) {
      src = (const f32x4*)x;
      j = i;
    } else if (i < n1 + n2) {
      src = (const f32x4*)wq;
      j = i - n1;
    } else {
      src = (const f32x4*)wp;
      j = i - n1 - n2;
    }
    f32x4 v = src[j];
    u16x4 o;
    o.x = f2bf(v.x);
    o.y = f2bf(v.y);
    o.z = f2bf(v.z);
    o.w = f2bf(v.w);
    ((u16x4*)out)[i] = o;
  }
}

// ---------------- GEMM: C[M][N] = A[M][K] * B[N][K]^T + bias ----------------
// 128x128 tile, BK=32, 4 waves, 16x16x32 MFMA, global_load_lds, 2-phase dbuf.
template <int WRITE_BF16>
__global__ __launch_bounds__(256) void gemm_bt(const u16* __restrict__ A,
                                               const u16* __restrict__ B,
                                               const float* __restrict__ bias,
                                               void* __restrict__ Cout,
                                               int M, int N, int K) {
  __shared__ u16 As[2][128 * 32];
  __shared__ u16 Bs[2][128 * 32];
  const int nb = N >> 7;
  const int bx = (int)blockIdx.x % nb;
  const int by = (int)blockIdx.x / nb;
  const int tid = threadIdx.x;
  const int lane = tid & 63;
  const int wv = tid >> 6;
  const int wr = wv >> 1, wc = wv & 1;

  f32x4 acc[4][4];
#pragma unroll
  for (int i = 0; i < 4; i++)
#pragma unroll
    for (int j = 0; j < 4; j++) acc[i][j] = (f32x4)(0.0f);

  const int e0 = tid * 8;
  const int r0 = e0 >> 5, c0 = e0 & 31;
  const u16* Ag0 = A + (size_t)(by * 128 + r0) * K + c0;
  const u16* Ag1 = A + (size_t)(by * 128 + r0 + 64) * K + c0;
  const u16* Bg0 = B + (size_t)(bx * 128 + r0) * K + c0;
  const u16* Bg1 = B + (size_t)(bx * 128 + r0 + 64) * K + c0;
  const int kc = (lane >> 4) * 8;
  const int wb = wv * 1024;

  gload_lds16(Ag0, (char*)As[0] + wb);
  gload_lds16(Ag1, (char*)As[0] + wb + 4096);
  gload_lds16(Bg0, (char*)Bs[0] + wb);
  gload_lds16(Bg1, (char*)Bs[0] + wb + 4096);
  __syncthreads();

  int cur = 0;
  for (int k0 = 0; k0 < K; k0 += 32) {
    const int nxt = cur ^ 1;
    if (k0 + 32 < K) {
      gload_lds16(Ag0 + k0 + 32, (char*)As[nxt] + wb);
      gload_lds16(Ag1 + k0 + 32, (char*)As[nxt] + wb + 4096);
      gload_lds16(Bg0 + k0 + 32, (char*)Bs[nxt] + wb);
      gload_lds16(Bg1 + k0 + 32, (char*)Bs[nxt] + wb + 4096);
    }
    const u16* Asc = As[cur];
    const u16* Bsc = Bs[cur];
    bf16x8 af[4], bfr[4];
#pragma unroll
    for (int mt = 0; mt < 4; mt++)
      af[mt] = *(const bf16x8*)&Asc[(wr * 64 + mt * 16 + (lane & 15)) * 32 + kc];
#pragma unroll
    for (int nt = 0; nt < 4; nt++)
      bfr[nt] = *(const bf16x8*)&Bsc[(wc * 64 + nt * 16 + (lane & 15)) * 32 + kc];
#pragma unroll
    for (int mt = 0; mt < 4; mt++)
#pragma unroll
      for (int nt = 0; nt < 4; nt++)
        acc[mt][nt] = __builtin_amdgcn_mfma_f32_16x16x32_bf16(af[mt], bfr[nt],
                                                              acc[mt][nt], 0, 0, 0);
    __syncthreads();
    cur = nxt;
  }

  const int colb = bx * 128 + wc * 64 + (lane & 15);
  const int rowb = by * 128 + wr * 64 + ((lane >> 4) << 2);
#pragma unroll
  for (int nt = 0; nt < 4; nt++) {
    const int col = colb + nt * 16;
    const float bv = bias[col];
#pragma unroll
    for (int mt = 0; mt < 4; mt++) {
#pragma unroll
      for (int r = 0; r < 4; r++) {
        const int row = rowb + mt * 16 + r;
        float v = acc[mt][nt][r] + bv;
        if (WRITE_BF16)
          ((u16*)Cout)[(size_t)row * N + col] = f2bf(v);
        else
          ((float*)Cout)[(size_t)row * N + col] = v;
      }
    }
  }
}

// ---------------- QK-RMSNorm + layout rearrange (bf16 qkv input) ------------
__global__ __launch_bounds__(256) void qkvnorm_kernel(const u16* __restrict__ qkv,
                                                      const float* __restrict__ gq,
                                                      const float* __restrict__ gk,
                                                      u16* __restrict__ Qh,
                                                      u16* __restrict__ Kh,
                                                      u16* __restrict__ Vt) {
  const int h = blockIdx.y;
  const int lblk = blockIdx.x * 64;
  const int tid = threadIdx.x;
  const int lane = tid & 63, wv = tid >> 6;
  __shared__ u16 vt[64][64];
  const float gqv = gq[lane] * 0.125f * 1.44269504088896f;  // 1/sqrt(HD) * log2(e)
  const float gkv = gk[lane];
#pragma unroll 1
  for (int i = 0; i < 16; i++) {
    const int l = lblk + wv * 16 + i;
    const size_t base = (size_t)l * NQKV + h * HD + lane;
    const float q = b2f(qkv[base]);
    const float k = b2f(qkv[base + DIM]);
    float sq = q * q, sk = k * k;
#pragma unroll
    for (int m = 32; m; m >>= 1) {
      sq += __shfl_xor(sq, m);
      sk += __shfl_xor(sk, m);
    }
    const float rq = rsqrtf(sq * (1.0f / 64.0f) + 1e-6f);
    const float rk = rsqrtf(sk * (1.0f / 64.0f) + 1e-6f);
    const size_t ho = ((size_t)h * L_SEQ + l) * HD + lane;
    Qh[ho] = f2bf(q * rq * gqv);
    Kh[ho] = f2bf(k * rk * gkv);
    vt[wv * 16 + i][lane] = qkv[base + 2 * DIM];
  }
  __syncthreads();
  const int d = tid >> 2;
  const int cb = (tid & 3) * 16;
  u16* dst = Vt + ((size_t)h * HD + d) * L_SEQ + lblk + cb;
#pragma unroll
  for (int j0 = 0; j0 < 4; j0++) {
    u16x4 o;
    o.x = vt[cb + j0 * 4 + 0][d];
    o.y = vt[cb + j0 * 4 + 1][d];
    o.z = vt[cb + j0 * 4 + 2][d];
    o.w = vt[cb + j0 * 4 + 3][d];
    *(u16x4*)(dst + j0 * 4) = o;
  }
}

// ---------------- MFMA flash, swapped-QK^T softmax, cvt_pk P-pack ------------
__global__ __launch_bounds__(256) void flash_kernel(const u16* __restrict__ Qh,
                                                    const u16* __restrict__ Kh,
                                                    const u16* __restrict__ Vt,
                                                    u16* __restrict__ O) {
  const int h = blockIdx.y;
  const int qblk = blockIdx.x * 64;
  const int tid = threadIdx.x;
  const int lane = tid & 63, wv = tid >> 6;
  __shared__ u16 Ks[64][64];     // [kv][d]
  __shared__ u16 Vs[64][64];     // [d][kv]
  __shared__ u16 Ps[4][16][64];  // per-wave [q][kv]

  const int l4 = lane & 15;
  const int g = lane >> 4;
  const int kc = g * 8;
  const int swz = (l4 & 7) << 3;  // row-determined swizzle (row ≡ l4 mod 8)

  const int qrow = qblk + wv * 16 + l4;
  const u16* Qp = Qh + ((size_t)h * L_SEQ + qrow) * HD;
  const bf16x8 qf0 = *(const bf16x8*)(Qp + kc);
  const bf16x8 qf1 = *(const bf16x8*)(Qp + 32 + kc);
  const bf16x8 ones = (bf16x8)(short)0x3F80;

  f32x4 oacc[4];
#pragma unroll
  for (int dt = 0; dt < 4; dt++) oacc[dt] = (f32x4)(0.0f);
  float mr = -1e30f;                   // running max for OWN q-row (q = l4)
  float lr[4] = {0.f, 0.f, 0.f, 0.f};  // denom for oacc rows (q = g*4+r)

  const int krow = tid >> 3;
  const int kcol = (tid & 7) * 8;
  const u16* Kg = Kh + (size_t)h * L_SEQ * HD + (size_t)krow * HD + kcol;
  u16* KsW0 = &Ks[krow][kcol ^ ((krow & 7) << 3)];
  u16* KsW1 = KsW0 + 32 * 64;
  const int vd = tid >> 2;
  const int vcol = (tid & 3) * 16;
  const u16* Vg = Vt + ((size_t)h * HD + vd) * L_SEQ;
  u16* VsW0 = &Vs[vd][vcol ^ ((vd & 7) << 3)];
  u16* VsW1 = &Vs[vd][(vcol + 8) ^ ((vd & 7) << 3)];

  bf16x8 kr0 = *(const bf16x8*)(Kg);
  bf16x8 kr1 = *(const bf16x8*)(Kg + 32 * HD);
  bf16x8 vr0 = *(const bf16x8*)(Vg + vcol);
  bf16x8 vr1 = *(const bf16x8*)(Vg + vcol + 8);

  for (int kb = 0; kb < L_SEQ; kb += 64) {
    __syncthreads();
    *(bf16x8*)KsW0 = kr0;
    *(bf16x8*)KsW1 = kr1;
    *(bf16x8*)VsW0 = vr0;
    *(bf16x8*)VsW1 = vr1;
    if (kb + 64 < L_SEQ) {  // T14 prefetch
      kr0 = *(const bf16x8*)(Kg + (size_t)(kb + 64) * HD);
      kr1 = *(const bf16x8*)(Kg + (size_t)(kb + 96) * HD);
      vr0 = *(const bf16x8*)(Vg + kb + 64 + vcol);
      vr1 = *(const bf16x8*)(Vg + kb + 72 + vcol);
    }
    __syncthreads();

    // QK^T swapped: s[st] = K_st * Q -> S^T
    f32x4 s[4];
    __builtin_amdgcn_s_setprio(1);
#pragma unroll
    for (int st = 0; st < 4; st++) {
      const u16* kp = &Ks[st * 16 + l4][0];
      bf16x8 ka = *(const bf16x8*)(kp + (kc ^ swz));
      bf16x8 kb2 = *(const bf16x8*)(kp + ((kc + 32) ^ swz));
      s[st] = __builtin_amdgcn_mfma_f32_16x16x32_bf16(ka, qf0, (f32x4)(0.0f), 0, 0, 0);
      s[st] = __builtin_amdgcn_mfma_f32_16x16x32_bf16(kb2, qf1, s[st], 0, 0, 0);
    }
    __builtin_amdgcn_s_setprio(0);

    // per-row max (q = l4): fused max3 chain + 2 cross-group shuffles
    float mx = fmaxf(fmaxf(s[0][0], s[0][1]), fmaxf(s[0][2], s[0][3]));
    mx = fmaxf(fmaxf(mx, s[1][0]), fmaxf(s[1][1], s[1][2]));
    mx = fmaxf(fmaxf(mx, s[1][3]), fmaxf(s[2][0], s[2][1]));
    mx = fmaxf(fmaxf(mx, s[2][2]), fmaxf(s[2][3], s[3][0]));
    mx = fmaxf(fmaxf(mx, s[3][1]), fmaxf(s[3][2], s[3][3]));
    mx = fmaxf(mx, __shfl_xor(mx, 16));
    mx = fmaxf(mx, __shfl_xor(mx, 32));

    // defer-max (T13, THR=8 in log2 domain: P bounded by 2^8)
    if (__any(mx > mr + 8.0f)) {
      const float nm = fmaxf(mr, mx);
      const float sclo = __builtin_amdgcn_exp2f(mr - nm);
      mr = nm;
      float scl[4];
#pragma unroll
      for (int r = 0; r < 4; r++) scl[r] = __shfl(sclo, g * 4 + r);
#pragma unroll
      for (int r = 0; r < 4; r++) lr[r] *= scl[r];
#pragma unroll
      for (int dt = 0; dt < 4; dt++)
#pragma unroll
        for (int r = 0; r < 4; r++) oacc[dt][r] *= scl[r];
    }

    // P = exp2(s - mr); packed via v_cvt_pk_bf16_f32 (RNE), 4x b64 writes
    u16* pr = &Ps[wv][l4][0];
#pragma unroll
    for (int st = 0; st < 4; st++) {
      uint2 pw;
      pw.x = cvt_pk_bf16(__builtin_amdgcn_exp2f(s[st][0] - mr),
                         __builtin_amdgcn_exp2f(s[st][1] - mr));
      pw.y = cvt_pk_bf16(__builtin_amdgcn_exp2f(s[st][2] - mr),
                         __builtin_amdgcn_exp2f(s[st][3] - mr));
      *(uint2*)(pr + ((st * 16 + g * 4) ^ swz)) = pw;
    }

    // PV + ones-MFMA row sums (Ps wave-private; in-wave DS ordering)
    const u16* pp = &Ps[wv][l4][0];
    bf16x8 pf0 = *(const bf16x8*)(pp + (kc ^ swz));
    bf16x8 pf1 = *(const bf16x8*)(pp + ((kc + 32) ^ swz));
    __builtin_amdgcn_s_setprio(1);
    f32x4 ls = __builtin_amdgcn_mfma_f32_16x16x32_bf16(pf0, ones, (f32x4)(0.0f), 0, 0, 0);
    ls = __builtin_amdgcn_mfma_f32_16x16x32_bf16(pf1, ones, ls, 0, 0, 0);
#pragma unroll
    for (int dt = 0; dt < 4; dt++) {
      const u16* vp = &Vs[dt * 16 + l4][0];
      bf16x8 vf0 = *(const bf16x8*)(vp + (kc ^ swz));
      bf16x8 vf1 = *(const bf16x8*)(vp + ((kc + 32) ^ swz));
      oacc[dt] = __builtin_amdgcn_mfma_f32_16x16x32_bf16(pf0, vf0, oacc[dt], 0, 0, 0);
      oacc[dt] = __builtin_amdgcn_mfma_f32_16x16x32_bf16(pf1, vf1, oacc[dt], 0, 0, 0);
    }
    __builtin_amdgcn_s_setprio(0);
#pragma unroll
    for (int r = 0; r < 4; r++) lr[r] += ls[r];
  }

#pragma unroll
  for (int r = 0; r < 4; r++) {
    const float inv = 1.0f / lr[r];
    const int row = qblk + wv * 16 + g * 4 + r;
#pragma unroll
    for (int dt = 0; dt < 4; dt++) {
      const int col = h * HD + dt * 16 + l4;
      O[(size_t)row * DIM + col] = f2bf(oacc[dt][r] * inv);
    }
  }
}

// ---------------- launcher ----------------
extern "C" void kernel_launch(void* const* d_in, const int* in_sizes, int n_in,
                              void* d_out, int out_size, void* d_ws, size_t ws_size,
                              hipStream_t stream) {
  const float* x = (const float*)d_in[0];
  const float* w_qkv = (const float*)d_in[1];
  const float* b_qkv = (const float*)d_in[2];
  const float* w_proj = (const float*)d_in[3];
  const float* b_proj = (const float*)d_in[4];
  const float* g_q = (const float*)d_in[5];
  const float* g_k = (const float*)d_in[6];

  char* ws = (char*)d_ws;
  u16* x_b = (u16*)(ws + 0);           // 6291456
  u16* wqkv_b = (u16*)(ws + 6291456);  // 14155776
  u16* wpj_b = (u16*)(ws + 20447232);  // 4718592
  u16* qkv = (u16*)(ws + 25165824);    // 18874368
  u16* Qh = (u16*)(ws + 44040192);     // 6291456
  u16* Kh = (u16*)(ws + 50331648);     // 6291456
  u16* Vt = (u16*)(ws + 56623104);     // 6291456
  u16* Ob = (u16*)(ws + 62914560);     // 6291456 -> total 69206016

  cast3_kernel<<<3072, 256, 0, stream>>>(x, w_qkv, w_proj, x_b);

  gemm_bt<1><<<(L_SEQ / 128) * (NQKV / 128), 256, 0, stream>>>(
      x_b, wqkv_b, b_qkv, (void*)qkv, L_SEQ, NQKV, DIM);

  qkvnorm_kernel<<<dim3(L_SEQ / 64, NH), 256, 0, stream>>>(qkv, g_q, g_k, Qh, Kh, Vt);

  flash_kernel<<<dim3(L_SEQ / 64, NH), 256, 0, stream>>>(Qh, Kh, Vt, Ob);

  // d_out is float32
  gemm_bt<0><<<(L_SEQ / 128) * (DIM / 128), 256, 0, stream>>>(
      Ob, wpj_b, b_proj, d_out, L_SEQ, DIM, DIM);
}

// Round 13
// 153.166 us; speedup vs baseline: 1.3772x; 1.0082x over previous
//
#include <hip/hip_runtime.h>
#include <stdint.h>

#define L_SEQ 2048
#define DIM 1536
#define NH 24
#define HD 64
#define NQKV 4608

typedef unsigned short u16;
typedef __attribute__((ext_vector_type(4))) float f32x4;
typedef __attribute__((ext_vector_type(8))) short bf16x8;
typedef __attribute__((ext_vector_type(4))) u16 u16x4;
typedef __attribute__((ext_vector_type(8))) u16 u16x8;

__device__ __forceinline__ u16 f2bf(float f) {
  unsigned u = __builtin_bit_cast(unsigned, f);
  u += 0x7fffu + ((u >> 16) & 1u);
  return (u16)(u >> 16);
}
__device__ __forceinline__ float b2f(u16 u) {
  return __builtin_bit_cast(float, (unsigned)u << 16);
}
__device__ __forceinline__ unsigned cvt_pk_bf16(float lo, float hi) {
  unsigned r;
  asm("v_cvt_pk_bf16_f32 %0, %1, %2" : "=v"(r) : "v"(lo), "v"(hi));
  return r;
}

__device__ __forceinline__ void gload_lds16(const void* g, void* lds) {
  __builtin_amdgcn_global_load_lds(
      (const __attribute__((address_space(1))) unsigned int*)g,
      (__attribute__((address_space(3))) unsigned int*)lds, 16, 0, 0);
}

// ---------------- fused cast f32 -> bf16 for x, w_qkv, w_proj ----------------
__global__ __launch_bounds__(256) void cast3_kernel(const float* __restrict__ x,
                                                    const float* __restrict__ wq,
                                                    const float* __restrict__ wp,
                                                    u16* __restrict__ out) {
  const int n1 = (L_SEQ * DIM) / 4;
  const int n2 = (NQKV * DIM) / 4;
  const int n3 = (DIM * DIM) / 4;
  const int tot = n1 + n2 + n3;
  for (int i = blockIdx.x * 256 + threadIdx.x; i < tot; i += gridDim.x * 256) {
    const f32x4* src;
    int j;
    if (i < n1) {
      src = (const f32x4*)x;
      j = i;
    } else if (i < n1 + n2) {
      src = (const f32x4*)wq;
      j = i - n1;
    } else {
      src = (const f32x4*)wp;
      j = i - n1 - n2;
    }
    f32x4 v = src[j];
    u16x4 o;
    o.x = f2bf(v.x);
    o.y = f2bf(v.y);
    o.z = f2bf(v.z);
    o.w = f2bf(v.w);
    ((u16x4*)out)[i] = o;
  }
}

// ---------------- GEMM: C[M][N] = A[M][K] * B[N][K]^T + bias ----------------
// 128x128 tile, BK=32, 4 waves, 16x16x32 MFMA, global_load_lds, 2-phase dbuf.
// XCD-bijective swizzle (grids are multiples of 8), by-fastest: each XCD keeps
// one B-column panel L2-resident.
template <int WRITE_BF16>
__global__ __launch_bounds__(256) void gemm_bt(const u16* __restrict__ A,
                                               const u16* __restrict__ B,
                                               const float* __restrict__ bias,
                                               void* __restrict__ Cout,
                                               int M, int N, int K) {
  __shared__ u16 As[2][128 * 32];
  __shared__ u16 Bs[2][128 * 32];
  const int mb = M >> 7;
  const int f = (int)blockIdx.x;
  const int f2 = (f & 7) * ((int)gridDim.x >> 3) + (f >> 3);
  const int bx = f2 / mb;  // col tile (slow within an XCD chunk)
  const int by = f2 % mb;  // row tile (fast)
  const int tid = threadIdx.x;
  const int lane = tid & 63;
  const int wv = tid >> 6;
  const int wr = wv >> 1, wc = wv & 1;

  f32x4 acc[4][4];
#pragma unroll
  for (int i = 0; i < 4; i++)
#pragma unroll
    for (int j = 0; j < 4; j++) acc[i][j] = (f32x4)(0.0f);

  const int e0 = tid * 8;
  const int r0 = e0 >> 5, c0 = e0 & 31;
  const u16* Ag0 = A + (size_t)(by * 128 + r0) * K + c0;
  const u16* Ag1 = A + (size_t)(by * 128 + r0 + 64) * K + c0;
  const u16* Bg0 = B + (size_t)(bx * 128 + r0) * K + c0;
  const u16* Bg1 = B + (size_t)(bx * 128 + r0 + 64) * K + c0;
  const int kc = (lane >> 4) * 8;
  const int wb = wv * 1024;

  gload_lds16(Ag0, (char*)As[0] + wb);
  gload_lds16(Ag1, (char*)As[0] + wb + 4096);
  gload_lds16(Bg0, (char*)Bs[0] + wb);
  gload_lds16(Bg1, (char*)Bs[0] + wb + 4096);
  __syncthreads();

  int cur = 0;
  for (int k0 = 0; k0 < K; k0 += 32) {
    const int nxt = cur ^ 1;
    if (k0 + 32 < K) {
      gload_lds16(Ag0 + k0 + 32, (char*)As[nxt] + wb);
      gload_lds16(Ag1 + k0 + 32, (char*)As[nxt] + wb + 4096);
      gload_lds16(Bg0 + k0 + 32, (char*)Bs[nxt] + wb);
      gload_lds16(Bg1 + k0 + 32, (char*)Bs[nxt] + wb + 4096);
    }
    const u16* Asc = As[cur];
    const u16* Bsc = Bs[cur];
    bf16x8 af[4], bfr[4];
#pragma unroll
    for (int mt = 0; mt < 4; mt++)
      af[mt] = *(const bf16x8*)&Asc[(wr * 64 + mt * 16 + (lane & 15)) * 32 + kc];
#pragma unroll
    for (int nt = 0; nt < 4; nt++)
      bfr[nt] = *(const bf16x8*)&Bsc[(wc * 64 + nt * 16 + (lane & 15)) * 32 + kc];
#pragma unroll
    for (int mt = 0; mt < 4; mt++)
#pragma unroll
      for (int nt = 0; nt < 4; nt++)
        acc[mt][nt] = __builtin_amdgcn_mfma_f32_16x16x32_bf16(af[mt], bfr[nt],
                                                              acc[mt][nt], 0, 0, 0);
    __syncthreads();
    cur = nxt;
  }

  const int colb = bx * 128 + wc * 64 + (lane & 15);
  const int rowb = by * 128 + wr * 64 + ((lane >> 4) << 2);
#pragma unroll
  for (int nt = 0; nt < 4; nt++) {
    const int col = colb + nt * 16;
    const float bv = bias[col];
#pragma unroll
    for (int mt = 0; mt < 4; mt++) {
#pragma unroll
      for (int r = 0; r < 4; r++) {
        const int row = rowb + mt * 16 + r;
        float v = acc[mt][nt][r] + bv;
        if (WRITE_BF16)
          ((u16*)Cout)[(size_t)row * N + col] = f2bf(v);
        else
          ((float*)Cout)[(size_t)row * N + col] = v;
      }
    }
  }
}

// ---------------- QK-RMSNorm + layout rearrange (bf16 qkv input) ------------
__global__ __launch_bounds__(256) void qkvnorm_kernel(const u16* __restrict__ qkv,
                                                      const float* __restrict__ gq,
                                                      const float* __restrict__ gk,
                                                      u16* __restrict__ Qh,
                                                      u16* __restrict__ Kh,
                                                      u16* __restrict__ Vt) {
  const int h = blockIdx.y;
  const int lblk = blockIdx.x * 64;
  const int tid = threadIdx.x;
  const int lane = tid & 63, wv = tid >> 6;
  __shared__ u16 vt[64][64];
  const float gqv = gq[lane] * 0.125f * 1.44269504088896f;  // 1/sqrt(HD) * log2(e)
  const float gkv = gk[lane];
#pragma unroll 1
  for (int i = 0; i < 16; i++) {
    const int l = lblk + wv * 16 + i;
    const size_t base = (size_t)l * NQKV + h * HD + lane;
    const float q = b2f(qkv[base]);
    const float k = b2f(qkv[base + DIM]);
    float sq = q * q, sk = k * k;
#pragma unroll
    for (int m = 32; m; m >>= 1) {
      sq += __shfl_xor(sq, m);
      sk += __shfl_xor(sk, m);
    }
    const float rq = rsqrtf(sq * (1.0f / 64.0f) + 1e-6f);
    const float rk = rsqrtf(sk * (1.0f / 64.0f) + 1e-6f);
    const size_t ho = ((size_t)h * L_SEQ + l) * HD + lane;
    Qh[ho] = f2bf(q * rq * gqv);
    Kh[ho] = f2bf(k * rk * gkv);
    vt[wv * 16 + i][lane] = qkv[base + 2 * DIM];
  }
  __syncthreads();
  const int d = tid >> 2;
  const int cb = (tid & 3) * 16;
  u16* dst = Vt + ((size_t)h * HD + d) * L_SEQ + lblk + cb;
#pragma unroll
  for (int j0 = 0; j0 < 4; j0++) {
    u16x4 o;
    o.x = vt[cb + j0 * 4 + 0][d];
    o.y = vt[cb + j0 * 4 + 1][d];
    o.z = vt[cb + j0 * 4 + 2][d];
    o.w = vt[cb + j0 * 4 + 3][d];
    *(u16x4*)(dst + j0 * 4) = o;
  }
}

// ---------------- MFMA flash, KVBLK=64 (R11-verified), XCD-swizzled ----------
// XCD swizzle: each XCD owns 3 whole heads -> K/V working set 1.5MB fits L2.
__global__ __launch_bounds__(256) void flash_kernel(const u16* __restrict__ Qh,
                                                    const u16* __restrict__ Kh,
                                                    const u16* __restrict__ Vt,
                                                    u16* __restrict__ O) {
  const int f = (int)blockIdx.y * (L_SEQ / 64) + (int)blockIdx.x;  // 0..767
  const int f2 = (f & 7) * 96 + (f >> 3);  // bijective (768 % 8 == 0)
  const int h = f2 >> 5;
  const int qblk = (f2 & 31) * 64;
  const int tid = threadIdx.x;
  const int lane = tid & 63, wv = tid >> 6;
  __shared__ u16 Ks[64][64];     // [kv][d]
  __shared__ u16 Vs[64][64];     // [d][kv]
  __shared__ u16 Ps[4][16][64];  // per-wave [q][kv]

  const int l4 = lane & 15;
  const int g = lane >> 4;
  const int kc = g * 8;
  const int swz = (l4 & 7) << 3;  // row-determined swizzle (row ≡ l4 mod 8)

  const int qrow = qblk + wv * 16 + l4;
  const u16* Qp = Qh + ((size_t)h * L_SEQ + qrow) * HD;
  const bf16x8 qf0 = *(const bf16x8*)(Qp + kc);
  const bf16x8 qf1 = *(const bf16x8*)(Qp + 32 + kc);
  const bf16x8 ones = (bf16x8)(short)0x3F80;

  f32x4 oacc[4];
#pragma unroll
  for (int dt = 0; dt < 4; dt++) oacc[dt] = (f32x4)(0.0f);
  float mr = -1e30f;                   // running max for OWN q-row (q = l4)
  float lr[4] = {0.f, 0.f, 0.f, 0.f};  // denom for oacc rows (q = g*4+r)

  const int krow = tid >> 3;
  const int kcol = (tid & 7) * 8;
  const u16* Kg = Kh + (size_t)h * L_SEQ * HD + (size_t)krow * HD + kcol;
  u16* KsW0 = &Ks[krow][kcol ^ ((krow & 7) << 3)];
  u16* KsW1 = KsW0 + 32 * 64;
  const int vd = tid >> 2;
  const int vcol = (tid & 3) * 16;
  const u16* Vg = Vt + ((size_t)h * HD + vd) * L_SEQ;
  u16* VsW0 = &Vs[vd][vcol ^ ((vd & 7) << 3)];
  u16* VsW1 = &Vs[vd][(vcol + 8) ^ ((vd & 7) << 3)];

  bf16x8 kr0 = *(const bf16x8*)(Kg);
  bf16x8 kr1 = *(const bf16x8*)(Kg + 32 * HD);
  bf16x8 vr0 = *(const bf16x8*)(Vg + vcol);
  bf16x8 vr1 = *(const bf16x8*)(Vg + vcol + 8);

  for (int kb = 0; kb < L_SEQ; kb += 64) {
    __syncthreads();
    *(bf16x8*)KsW0 = kr0;
    *(bf16x8*)KsW1 = kr1;
    *(bf16x8*)VsW0 = vr0;
    *(bf16x8*)VsW1 = vr1;
    if (kb + 64 < L_SEQ) {  // T14 prefetch
      kr0 = *(const bf16x8*)(Kg + (size_t)(kb + 64) * HD);
      kr1 = *(const bf16x8*)(Kg + (size_t)(kb + 96) * HD);
      vr0 = *(const bf16x8*)(Vg + kb + 64 + vcol);
      vr1 = *(const bf16x8*)(Vg + kb + 72 + vcol);
    }
    __syncthreads();

    // QK^T swapped: s[st] = K_st * Q -> S^T
    f32x4 s[4];
    __builtin_amdgcn_s_setprio(1);
#pragma unroll
    for (int st = 0; st < 4; st++) {
      const u16* kp = &Ks[st * 16 + l4][0];
      bf16x8 ka = *(const bf16x8*)(kp + (kc ^ swz));
      bf16x8 kb2 = *(const bf16x8*)(kp + ((kc + 32) ^ swz));
      s[st] = __builtin_amdgcn_mfma_f32_16x16x32_bf16(ka, qf0, (f32x4)(0.0f), 0, 0, 0);
      s[st] = __builtin_amdgcn_mfma_f32_16x16x32_bf16(kb2, qf1, s[st], 0, 0, 0);
    }
    __builtin_amdgcn_s_setprio(0);

    // per-row max (q = l4): fused max chain + 2 cross-group shuffles
    float mx = fmaxf(fmaxf(s[0][0], s[0][1]), fmaxf(s[0][2], s[0][3]));
    mx = fmaxf(fmaxf(mx, s[1][0]), fmaxf(s[1][1], s[1][2]));
    mx = fmaxf(fmaxf(mx, s[1][3]), fmaxf(s[2][0], s[2][1]));
    mx = fmaxf(fmaxf(mx, s[2][2]), fmaxf(s[2][3], s[3][0]));
    mx = fmaxf(fmaxf(mx, s[3][1]), fmaxf(s[3][2], s[3][3]));
    mx = fmaxf(mx, __shfl_xor(mx, 16));
    mx = fmaxf(mx, __shfl_xor(mx, 32));

    // defer-max (T13, THR=8 in log2 domain: P bounded by 2^8)
    if (__any(mx > mr + 8.0f)) {
      const float nm = fmaxf(mr, mx);
      const float sclo = __builtin_amdgcn_exp2f(mr - nm);
      mr = nm;
      float scl[4];
#pragma unroll
      for (int r = 0; r < 4; r++) scl[r] = __shfl(sclo, g * 4 + r);
#pragma unroll
      for (int r = 0; r < 4; r++) lr[r] *= scl[r];
#pragma unroll
      for (int dt = 0; dt < 4; dt++)
#pragma unroll
        for (int r = 0; r < 4; r++) oacc[dt][r] *= scl[r];
    }

    // P = exp2(s - mr); packed via v_cvt_pk_bf16_f32 (RNE), 4x b64 writes
    u16* pr = &Ps[wv][l4][0];
#pragma unroll
    for (int st = 0; st < 4; st++) {
      uint2 pw;
      pw.x = cvt_pk_bf16(__builtin_amdgcn_exp2f(s[st][0] - mr),
                         __builtin_amdgcn_exp2f(s[st][1] - mr));
      pw.y = cvt_pk_bf16(__builtin_amdgcn_exp2f(s[st][2] - mr),
                         __builtin_amdgcn_exp2f(s[st][3] - mr));
      *(uint2*)(pr + ((st * 16 + g * 4) ^ swz)) = pw;
    }

    // PV + ones-MFMA row sums (Ps wave-private; in-wave DS ordering)
    const u16* pp = &Ps[wv][l4][0];
    bf16x8 pf0 = *(const bf16x8*)(pp + (kc ^ swz));
    bf16x8 pf1 = *(const bf16x8*)(pp + ((kc + 32) ^ swz));
    __builtin_amdgcn_s_setprio(1);
    f32x4 ls = __builtin_amdgcn_mfma_f32_16x16x32_bf16(pf0, ones, (f32x4)(0.0f), 0, 0, 0);
    ls = __builtin_amdgcn_mfma_f32_16x16x32_bf16(pf1, ones, ls, 0, 0, 0);
#pragma unroll
    for (int dt = 0; dt < 4; dt++) {
      const u16* vp = &Vs[dt * 16 + l4][0];
      bf16x8 vf0 = *(const bf16x8*)(vp + (kc ^ swz));
      bf16x8 vf1 = *(const bf16x8*)(vp + ((kc + 32) ^ swz));
      oacc[dt] = __builtin_amdgcn_mfma_f32_16x16x32_bf16(pf0, vf0, oacc[dt], 0, 0, 0);
      oacc[dt] = __builtin_amdgcn_mfma_f32_16x16x32_bf16(pf1, vf1, oacc[dt], 0, 0, 0);
    }
    __builtin_amdgcn_s_setprio(0);
#pragma unroll
    for (int r = 0; r < 4; r++) lr[r] += ls[r];
  }

#pragma unroll
  for (int r = 0; r < 4; r++) {
    const float inv = 1.0f / lr[r];
    const int row = qblk + wv * 16 + g * 4 + r;
#pragma unroll
    for (int dt = 0; dt < 4; dt++) {
      const int col = h * HD + dt * 16 + l4;
      O[(size_t)row * DIM + col] = f2bf(oacc[dt][r] * inv);
    }
  }
}

// ---------------- launcher ----------------
extern "C" void kernel_launch(void* const* d_in, const int* in_sizes, int n_in,
                              void* d_out, int out_size, void* d_ws, size_t ws_size,
                              hipStream_t stream) {
  const float* x = (const float*)d_in[0];
  const float* w_qkv = (const float*)d_in[1];
  const float* b_qkv = (const float*)d_in[2];
  const float* w_proj = (const float*)d_in[3];
  const float* b_proj = (const float*)d_in[4];
  const float* g_q = (const float*)d_in[5];
  const float* g_k = (const float*)d_in[6];

  char* ws = (char*)d_ws;
  u16* x_b = (u16*)(ws + 0);           // 6291456
  u16* wqkv_b = (u16*)(ws + 6291456);  // 14155776
  u16* wpj_b = (u16*)(ws + 20447232);  // 4718592
  u16* qkv = (u16*)(ws + 25165824);    // 18874368
  u16* Qh = (u16*)(ws + 44040192);     // 6291456
  u16* Kh = (u16*)(ws + 50331648);     // 6291456
  u16* Vt = (u16*)(ws + 56623104);     // 6291456
  u16* Ob = (u16*)(ws + 62914560);     // 6291456 -> total 69206016

  cast3_kernel<<<3072, 256, 0, stream>>>(x, w_qkv, w_proj, x_b);

  gemm_bt<1><<<(L_SEQ / 128) * (NQKV / 128), 256, 0, stream>>>(
      x_b, wqkv_b, b_qkv, (void*)qkv, L_SEQ, NQKV, DIM);

  qkvnorm_kernel<<<dim3(L_SEQ / 64, NH), 256, 0, stream>>>(qkv, g_q, g_k, Qh, Kh, Vt);

  flash_kernel<<<dim3(L_SEQ / 64, NH), 256, 0, stream>>>(Qh, Kh, Vt, Ob);

  // d_out is float32
  gemm_bt<0><<<(L_SEQ / 128) * (DIM / 128), 256, 0, stream>>>(
      Ob, wpj_b, b_proj, d_out, L_SEQ, DIM, DIM);
}